// Round 11
// baseline (772.532 us; speedup 1.0000x reference)
//
#include <hip/hip_runtime.h>
#include <hip/hip_cooperative_groups.h>

namespace cg = cooperative_groups;

#define GRID_BLOCKS 512

// ---------------------------------------------------------------------------
// GEMM body: out[r0..r0+7, 0..255] = bn_relu?(in rows) @ W(128x256) + bias.
// 8 rows/block, thread = 2 rows x 4 cols. st: raw per-channel sum/sumsq.
// ---------------------------------------------------------------------------
__device__ __forceinline__ void do_gemm(
    const float* __restrict__ in, const float* __restrict__ st,
    const float* __restrict__ gm, const float* __restrict__ bt,
    const float* __restrict__ W, const float* __restrict__ bi,
    float* __restrict__ out, int rb, char* smemc)
{
    float* rows  = (float*)smemc;           // 8*128 floats = 4 KB
    float* scale = rows + 1024;             // 128
    float* shift = scale + 128;             // 128
    int t = threadIdx.x;
    if (t < 128) {
        float sc = 1.0f, sf = 0.0f;
        if (st) {
            float mu  = st[t] * (1.0f/2048.0f);
            float var = st[128+t] * (1.0f/2048.0f) - mu*mu;
            sc = rsqrtf(var + 1e-5f) * gm[t];
            sf = bt[t] - mu*sc;
        }
        scale[t] = sc; shift[t] = sf;
    }
    __syncthreads();
    int r0 = rb * 8;
    {
        float4 v = ((const float4*)(in + r0*128))[t];
        if (st) {
            int c4 = (t & 31) << 2;
            v.x = fmaxf(v.x*scale[c4  ] + shift[c4  ], 0.0f);
            v.y = fmaxf(v.y*scale[c4+1] + shift[c4+1], 0.0f);
            v.z = fmaxf(v.z*scale[c4+2] + shift[c4+2], 0.0f);
            v.w = fmaxf(v.w*scale[c4+3] + shift[c4+3], 0.0f);
        }
        ((float4*)rows)[t] = v;
    }
    __syncthreads();
    int cb = t & 63, rp = (t >> 6) << 1;
    const float* a0r = rows + rp*128;
    const float* a1r = a0r + 128;
    const float4* W4 = (const float4*)W;
    float4 acc0 = make_float4(0.f,0.f,0.f,0.f);
    float4 acc1 = make_float4(0.f,0.f,0.f,0.f);
    #pragma unroll 4
    for (int k = 0; k < 128; k += 4) {
        float4 a0 = *(const float4*)(a0r + k);
        float4 a1 = *(const float4*)(a1r + k);
        float4 w;
        w = W4[(k+0)*64+cb];
        acc0.x += a0.x*w.x; acc0.y += a0.x*w.y; acc0.z += a0.x*w.z; acc0.w += a0.x*w.w;
        acc1.x += a1.x*w.x; acc1.y += a1.x*w.y; acc1.z += a1.x*w.z; acc1.w += a1.x*w.w;
        w = W4[(k+1)*64+cb];
        acc0.x += a0.y*w.x; acc0.y += a0.y*w.y; acc0.z += a0.y*w.z; acc0.w += a0.y*w.w;
        acc1.x += a1.y*w.x; acc1.y += a1.y*w.y; acc1.z += a1.y*w.z; acc1.w += a1.y*w.w;
        w = W4[(k+2)*64+cb];
        acc0.x += a0.z*w.x; acc0.y += a0.z*w.y; acc0.z += a0.z*w.z; acc0.w += a0.z*w.w;
        acc1.x += a1.z*w.x; acc1.y += a1.z*w.y; acc1.z += a1.z*w.z; acc1.w += a1.z*w.w;
        w = W4[(k+3)*64+cb];
        acc0.x += a0.w*w.x; acc0.y += a0.w*w.y; acc0.z += a0.w*w.z; acc0.w += a0.w*w.w;
        acc1.x += a1.w*w.x; acc1.y += a1.w*w.y; acc1.z += a1.w*w.z; acc1.w += a1.w*w.w;
    }
    float4 b4 = ((const float4*)bi)[cb];
    acc0.x += b4.x; acc0.y += b4.y; acc0.z += b4.z; acc0.w += b4.w;
    acc1.x += b4.x; acc1.y += b4.y; acc1.z += b4.z; acc1.w += b4.w;
    ((float4*)out)[(r0+rp  )*64 + cb] = acc0;
    ((float4*)out)[(r0+rp+1)*64 + cb] = acc1;
}

// ---------------------------------------------------------------------------
// Wave-synchronous knn for 4 vertices (1/wave). Same algorithm that passed
// rounds 8-10: hist + shfl_up radix-select rank-101, compact, register
// bitonic-256. Key=(sortable_dist<<32)|idx == jax top_k order incl. ties.
// ---------------------------------------------------------------------------
__device__ __forceinline__ void knn_item(
    int blk, const float* __restrict__ verts, int* __restrict__ idxout,
    char* smem)
{
    float* xs  = (float*)smem;                     // [0,4K)
    float* ys  = xs + 1024;                        // [4K,8K)
    float* zs  = ys + 1024;                        // [8K,12K)
    float* sqs = zs + 1024;                        // [12K,16K)
    unsigned int* histBase = (unsigned int*)(smem + 16384);   // [16K,20K)
    unsigned int* selBase  = (unsigned int*)(smem + 20480);   // 64 B

    int t = threadIdx.x;
    int w = t >> 6, l = t & 63;
    int vglob = blk*4 + w;
    int b = vglob >> 10;
    int v = vglob & 1023;
    unsigned long long* keys = (unsigned long long*)smem + w*256;  // alias xs/ys
    unsigned int* hist = histBase + w*256;
    unsigned int* sel  = selBase + w*4;

    const float* vb = verts + b * 3072;
    for (int i = t; i < 1024; i += 256) {
        float xx = vb[i*3+0], yy = vb[i*3+1], zz = vb[i*3+2];
        xs[i] = xx; ys[i] = yy; zs[i] = zz;
        sqs[i] = xx*xx + yy*yy + zz*zz;
    }
    __syncthreads();

    float cx = xs[v], cy = ys[v], cz = zs[v], csq = sqs[v];
    unsigned long long K16[16];
    #pragma unroll
    for (int q = 0; q < 16; ++q) {
        int j = q*64 + l;
        float dot = cx*xs[j] + cy*ys[j] + cz*zs[j];
        float d = -2.0f*dot + csq + sqs[j];
        unsigned int u = __float_as_uint(d);
        u = (u & 0x80000000u) ? ~u : (u | 0x80000000u);
        K16[q] = (((unsigned long long)u) << 32) | (unsigned long long)j;
    }
    #pragma unroll
    for (int i = 0; i < 4; ++i) hist[l*4 + i] = 0u;
    __syncthreads();

    #pragma unroll
    for (int q = 0; q < 16; ++q)
        atomicAdd(&hist[(unsigned int)(K16[q] >> 56)], 1u);
    __syncthreads();

    {
        unsigned int h0 = hist[l*4], h1 = hist[l*4+1], h2 = hist[l*4+2], h3 = hist[l*4+3];
        unsigned int c1 = h0, c2 = h0+h1, c3 = h0+h1+h2, T = c3+h3;
        unsigned int xacc = T;
        #pragma unroll
        for (int off = 1; off < 64; off <<= 1) {
            unsigned int y = __shfl_up(xacc, off, 64);
            if (l >= off) xacc += y;
        }
        unsigned int P = xacc - T;
        unsigned int ex[4] = {P, P+c1, P+c2, P+c3};
        unsigned int hh[4] = {h0, h1, h2, h3};
        #pragma unroll
        for (int i = 0; i < 4; ++i) {
            if (ex[i] < 101u && ex[i] + hh[i] >= 101u) {
                sel[0] = (unsigned int)(l*4 + i);
                sel[1] = 101u - ex[i];
            }
        }
    }
    __syncthreads();
    unsigned int P8 = sel[0], rank2 = sel[1];
    #pragma unroll
    for (int i = 0; i < 4; ++i) hist[l*4 + i] = 0u;
    __syncthreads();

    #pragma unroll
    for (int q = 0; q < 16; ++q)
        if ((unsigned int)(K16[q] >> 56) == P8)
            atomicAdd(&hist[(unsigned int)(K16[q] >> 48) & 0xFFu], 1u);
    __syncthreads();

    {
        unsigned int h0 = hist[l*4], h1 = hist[l*4+1], h2 = hist[l*4+2], h3 = hist[l*4+3];
        unsigned int c1 = h0, c2 = h0+h1, c3 = h0+h1+h2, T = c3+h3;
        unsigned int xacc = T;
        #pragma unroll
        for (int off = 1; off < 64; off <<= 1) {
            unsigned int y = __shfl_up(xacc, off, 64);
            if (l >= off) xacc += y;
        }
        unsigned int P = xacc - T;
        unsigned int ex[4] = {P, P+c1, P+c2, P+c3};
        unsigned int hh[4] = {h0, h1, h2, h3};
        #pragma unroll
        for (int i = 0; i < 4; ++i) {
            if (ex[i] < rank2 && ex[i] + hh[i] >= rank2) {
                sel[2] = (P8 << 8) | (unsigned int)(l*4 + i);
                sel[3] = 0u;
            }
        }
    }
    __syncthreads();
    unsigned int P16 = sel[2];

    #pragma unroll
    for (int q = 0; q < 16; ++q) {
        if ((unsigned int)(K16[q] >> 48) <= P16) {
            unsigned int pos = atomicAdd(&sel[3], 1u);
            if (pos < 256u) keys[pos] = K16[q];
        }
    }
    __syncthreads();
    unsigned int cnt = sel[3];

    unsigned long long K[4];
    #pragma unroll
    for (int q = 0; q < 4; ++q) {
        unsigned int e = (unsigned int)(l*4 + q);
        K[q] = (e < cnt) ? keys[e] : 0xFFFFFFFFFFFFFFFFULL;
    }

    auto cswap = [&](int qa, int qb, int k) {
        int e = (l << 2) + qa;
        bool up = ((e & k) == 0);
        unsigned long long a = K[qa], bb2 = K[qb];
        unsigned long long mn = a < bb2 ? a : bb2;
        unsigned long long mx = a < bb2 ? bb2 : a;
        K[qa] = up ? mn : mx;
        K[qb] = up ? mx : mn;
    };
    #pragma unroll
    for (int k = 2; k <= 256; k <<= 1) {
        for (int j = k >> 1; j >= 4; j >>= 1) {
            int lj = j >> 2;
            #pragma unroll
            for (int q = 0; q < 4; ++q) {
                unsigned long long other = __shfl_xor(K[q], lj, 64);
                int e = (l << 2) + q;
                bool up = ((e & k) == 0);
                bool lower = ((l & lj) == 0);
                bool takeMin = (lower == up);
                unsigned long long mn = K[q] < other ? K[q] : other;
                unsigned long long mx = K[q] < other ? other : K[q];
                K[q] = takeMin ? mn : mx;
            }
        }
        if (k >= 4) { cswap(0, 2, k); cswap(1, 3, k); }
        cswap(0, 1, k); cswap(2, 3, k);
    }

    #pragma unroll
    for (int q = 0; q < 4; ++q) {
        int e = l*4 + q;
        if (e >= 1 && e <= 100)
            idxout[vglob*100 + (e-1)] = (int)(K[q] & 0xFFFFFFFFu);
    }
}

// ---------------------------------------------------------------------------
// Agg for one row, executed by a 128-thread half-block (tt = t&127).
// ---------------------------------------------------------------------------
__device__ __forceinline__ void agg_row(
    const int* __restrict__ idx, const float* __restrict__ verts,
    const float* __restrict__ sd, const float* __restrict__ fos, int n,
    float* __restrict__ outp, int r, int tt, float4* ds4, int* js)
{
    int b = r >> 10;
    if (tt < n) {
        int j = idx[r*100 + tt];
        js[tt] = j;
        const float* pj = verts + (b*1024 + j)*3;
        const float* pv = verts + r*3;
        float dx = pj[0]-pv[0], dy = pj[1]-pv[1], dz = pj[2]-pv[2];
        float nm = sqrtf(dx*dx + dy*dy + dz*dz);
        float inv = 1.0f / fmaxf(nm, 1e-12f);
        ds4[tt] = make_float4(dx*inv, dy*inv, dz*inv, 0.0f);
    }
    __syncthreads();
    float s0 = sd[tt], s1 = sd[128+tt], s2 = sd[256+tt];
    int bb = b * 1024;
    float m = -3.0e38f;
    for (int q = 0; q < n; q += 5) {
        float th[5];
        const float* p[5];
        #pragma unroll
        for (int u = 0; u < 5; ++u) {
            float4 dq = ds4[q+u];
            th[u] = fmaxf(dq.x*s0 + dq.y*s1 + dq.z*s2, 0.0f);
            p[u] = fos + (size_t)(bb + js[q+u])*256 + 128 + tt;
        }
        float vv[5];
        #pragma unroll
        for (int u = 0; u < 5; ++u) vv[u] = *p[u];
        #pragma unroll
        for (int u = 0; u < 5; ++u) m = fmaxf(m, th[u]*vv[u]);
    }
    outp[r*128 + tt] = fos[r*256 + tt] + m;
}

// ---------------------------------------------------------------------------
// Stats for one 128-row slice (sub in [0,16)), 256 threads.
// ---------------------------------------------------------------------------
__device__ __forceinline__ void stats_item(
    const float* __restrict__ p, float* __restrict__ stL, int sub, char* smem)
{
    float* s1 = (float*)smem;
    float* s2 = s1 + 256;
    int t = threadIdx.x, k = t & 127, half = t >> 7;
    int r0 = sub * 128;
    float sum = 0.0f, sq = 0.0f;
    for (int s = 0; s < 64; ++s) {
        float xv = p[(r0 + half + 2*s)*128 + k];
        sum += xv; sq += xv*xv;
    }
    s1[t] = sum; s2[t] = sq;
    __syncthreads();
    if (t < 128) {
        atomicAdd(&stL[k],     s1[t] + s1[t+128]);
        atomicAdd(&stL[128+k], s2[t] + s2[t+128]);
    }
}

// ---------------------------------------------------------------------------
// Down-proj for 8 rows (item wi): [bn(pa)|bn(pb)|bn(pc)] @ dW + db, relu.
// ---------------------------------------------------------------------------
__device__ __forceinline__ void down_item(
    const float* __restrict__ pa, const float* __restrict__ sta,
    const float* __restrict__ ga, const float* __restrict__ bea,
    const float* __restrict__ pb, const float* __restrict__ stb,
    const float* __restrict__ gb, const float* __restrict__ beb,
    const float* __restrict__ pc, const float* __restrict__ stc,
    const float* __restrict__ gc, const float* __restrict__ bec,
    const float* __restrict__ dW, const float* __restrict__ db,
    float* __restrict__ out, int wi, char* smem)
{
    float* rows  = (float*)smem;            // 8*384 floats = 12288 B
    float* scale = rows + 3072;             // 384
    float* shift = scale + 384;             // 384
    int t = threadIdx.x;
    int r0 = wi * 8;
    for (int c = t; c < 384; c += 256) {
        int seg = c >> 7, cc = c & 127;
        const float* stp = seg==0 ? sta : seg==1 ? stb : stc;
        const float* g   = seg==0 ? ga  : seg==1 ? gb  : gc;
        const float* be  = seg==0 ? bea : seg==1 ? beb : bec;
        float mu  = stp[cc] * (1.0f/2048.0f);
        float var = stp[128+cc] * (1.0f/2048.0f) - mu*mu;
        float s = rsqrtf(var + 1e-5f) * g[cc];
        scale[c] = s;
        shift[c] = be[cc] - mu*s;
    }
    __syncthreads();
    for (int q = t; q < 768; q += 256) {
        int row = q / 96, rem = q - row*96;
        int c4 = rem << 2;
        int seg = c4 >> 7, cc = c4 & 127;
        const float* ps = seg==0 ? pa : seg==1 ? pb : pc;
        float4 v = *(const float4*)(ps + (r0+row)*128 + cc);
        v.x = fmaxf(v.x*scale[c4  ] + shift[c4  ], 0.0f);
        v.y = fmaxf(v.y*scale[c4+1] + shift[c4+1], 0.0f);
        v.z = fmaxf(v.z*scale[c4+2] + shift[c4+2], 0.0f);
        v.w = fmaxf(v.w*scale[c4+3] + shift[c4+3], 0.0f);
        *(float4*)&rows[row*384 + c4] = v;
    }
    __syncthreads();
    int cb = t & 63, rp = (t >> 6) << 1;
    const float* a0r = rows + rp*384;
    const float* a1r = a0r + 384;
    const float4* W4 = (const float4*)dW;
    float4 acc0 = make_float4(0.f,0.f,0.f,0.f);
    float4 acc1 = make_float4(0.f,0.f,0.f,0.f);
    #pragma unroll 4
    for (int k = 0; k < 384; k += 4) {
        float4 a0 = *(const float4*)(a0r + k);
        float4 a1 = *(const float4*)(a1r + k);
        float4 w;
        w = W4[(k+0)*64+cb];
        acc0.x += a0.x*w.x; acc0.y += a0.x*w.y; acc0.z += a0.x*w.z; acc0.w += a0.x*w.w;
        acc1.x += a1.x*w.x; acc1.y += a1.x*w.y; acc1.z += a1.x*w.z; acc1.w += a1.x*w.w;
        w = W4[(k+1)*64+cb];
        acc0.x += a0.y*w.x; acc0.y += a0.y*w.y; acc0.z += a0.y*w.z; acc0.w += a0.y*w.w;
        acc1.x += a1.y*w.x; acc1.y += a1.y*w.y; acc1.z += a1.y*w.z; acc1.w += a1.y*w.w;
        w = W4[(k+2)*64+cb];
        acc0.x += a0.z*w.x; acc0.y += a0.z*w.y; acc0.z += a0.z*w.z; acc0.w += a0.z*w.w;
        acc1.x += a1.z*w.x; acc1.y += a1.z*w.y; acc1.z += a1.z*w.z; acc1.w += a1.z*w.w;
        w = W4[(k+3)*64+cb];
        acc0.x += a0.w*w.x; acc0.y += a0.w*w.y; acc0.z += a0.w*w.z; acc0.w += a0.w*w.w;
        acc1.x += a1.w*w.x; acc1.y += a1.w*w.y; acc1.z += a1.w*w.z; acc1.w += a1.w*w.w;
    }
    float4 b4 = ((const float4*)db)[cb];
    float4 o0, o1;
    o0.x = fmaxf(acc0.x + b4.x, 0.0f); o0.y = fmaxf(acc0.y + b4.y, 0.0f);
    o0.z = fmaxf(acc0.z + b4.z, 0.0f); o0.w = fmaxf(acc0.w + b4.w, 0.0f);
    o1.x = fmaxf(acc1.x + b4.x, 0.0f); o1.y = fmaxf(acc1.y + b4.y, 0.0f);
    o1.z = fmaxf(acc1.z + b4.z, 0.0f); o1.w = fmaxf(acc1.w + b4.w, 0.0f);
    ((float4*)out)[(r0+rp  )*64 + cb] = o0;
    ((float4*)out)[(r0+rp+1)*64 + cb] = o1;
}

// ---------------------------------------------------------------------------
// Mega kernel: 10 phases separated by grid.sync(). Grid = 512x256 (coop).
// ---------------------------------------------------------------------------
__global__ void mega_kernel(
    const float* __restrict__ verts, const float* __restrict__ x,
    const float* __restrict__ convW, const float* __restrict__ convB,
    const float* __restrict__ dirs,  const float* __restrict__ gam,
    const float* __restrict__ bet,   const float* __restrict__ dW,
    const float* __restrict__ db,    float* __restrict__ out,
    int* __restrict__ idxb, float* __restrict__ sdn,
    float* __restrict__ st, float* __restrict__ fo, float* __restrict__ pbuf)
{
    cg::grid_group grid = cg::this_grid();
    __shared__ __align__(16) char smem[20544];
    int bid = blockIdx.x, t = threadIdx.x;
    int h = t >> 7, tt = t & 127;
    float4* ds4 = (float4*)smem + h*100;           // agg: 2 halves x 100 float4
    int* js = (int*)(smem + 3200) + h*100;

    // ---- P1: knn (0..511) + gemmA (512..1279) + zero st + dirs norm
    for (int wi = bid; wi < 1287; wi += GRID_BLOCKS) {
        if (wi < 512) {
            knn_item(wi, verts, idxb, smem);
        } else if (wi < 1280) {
            int g = wi - 512;
            int s = g >> 8, rb = g & 255;
            int wsel = (s==0) ? 0 : (s==1) ? 1 : 3;
            do_gemm(x, (const float*)0, (const float*)0, (const float*)0,
                    convW + wsel*32768, convB + wsel*256, fo + s*524288, rb, smem);
        } else if (wi < 1286) {
            st[(wi - 1280)*256 + t] = 0.0f;
        } else {
            for (int i = t; i < 768; i += 256) {
                int l = i >> 7, k = i & 127;
                float a = dirs[l*384 + k];
                float b = dirs[l*384 + 128 + k];
                float c = dirs[l*384 + 256 + k];
                float nrm = sqrtf(a*a + b*b + c*c);
                float inv = 1.0f / fmaxf(nrm, 1e-12f);
                sdn[l*384 + k]       = a*inv;
                sdn[l*384 + 128 + k] = b*inv;
                sdn[l*384 + 256 + k] = c*inv;
            }
        }
        __syncthreads();
    }
    grid.sync();

    // ---- P2: aggA -- slots {L0:n5,d0,buf0} {L1:n20,d1,buf1} {L3:n100,d3,buf3}
    for (int p = bid; p < 3072; p += GRID_BLOCKS) {
        int item = p*2 + h;
        int slot = item >> 11, r = item & 2047;
        int n    = slot==0 ? 5 : slot==1 ? 20 : 100;
        int dsel = slot==0 ? 0 : slot==1 ? 1 : 3;
        agg_row(idxb, verts, sdn + dsel*384, fo + slot*524288, n,
                pbuf + dsel*262144, r, tt, ds4, js);
        __syncthreads();
    }
    grid.sync();

    // ---- P3: statsA (layers 0,1,3)
    for (int wi = bid; wi < 48; wi += GRID_BLOCKS) {
        int s = wi >> 4, sub = wi & 15;
        int lsel = (s==0) ? 0 : (s==1) ? 1 : 3;
        stats_item(pbuf + lsel*262144, st + lsel*256, sub, smem);
        __syncthreads();
    }
    grid.sync();

    // ---- P4: gemmB -- L2 from bn(buf1,st1,g1,b1); L4 from bn(buf3,st3,g3,b3)
    for (int wi = bid; wi < 512; wi += GRID_BLOCKS) {
        int s = wi >> 8, rb = wi & 255;
        if (s == 0)
            do_gemm(pbuf + 1*262144, st + 256, gam + 128, bet + 128,
                    convW + 65536, convB + 512, fo, rb, smem);
        else
            do_gemm(pbuf + 3*262144, st + 768, gam + 384, bet + 384,
                    convW + 131072, convB + 1024, fo + 524288, rb, smem);
        __syncthreads();
    }
    grid.sync();

    // ---- P5: aggB -- {L2:n20,d2,buf2,fo0} {L4:n100,d4,buf4,fo1}
    for (int p = bid; p < 2048; p += GRID_BLOCKS) {
        int item = p*2 + h;
        int slot = item >> 11, r = item & 2047;
        int n    = slot==0 ? 20 : 100;
        int dsel = slot==0 ? 2 : 4;
        agg_row(idxb, verts, sdn + dsel*384, fo + slot*524288, n,
                pbuf + dsel*262144, r, tt, ds4, js);
        __syncthreads();
    }
    grid.sync();

    // ---- P6: statsB (layers 2,4)
    for (int wi = bid; wi < 32; wi += GRID_BLOCKS) {
        int s = wi >> 4, sub = wi & 15;
        int lsel = (s==0) ? 2 : 4;
        stats_item(pbuf + lsel*262144, st + lsel*256, sub, smem);
        __syncthreads();
    }
    grid.sync();

    // ---- P7: gemmC -- L5-conv (W params3) from bn(buf4,st4,g4,b4)
    for (int wi = bid; wi < 256; wi += GRID_BLOCKS) {
        do_gemm(pbuf + 4*262144, st + 1024, gam + 512, bet + 512,
                convW + 98304, convB + 768, fo, wi, smem);
        __syncthreads();
    }
    grid.sync();

    // ---- P8: aggC -- n100, d3, fo0 -> buf5
    for (int p = bid; p < 1024; p += GRID_BLOCKS) {
        int item = p*2 + h;
        int r = item & 2047;
        agg_row(idxb, verts, sdn + 3*384, fo, 100,
                pbuf + 5*262144, r, tt, ds4, js);
        __syncthreads();
    }
    grid.sync();

    // ---- P9: statsC (layer 5 -> st+1280)
    for (int wi = bid; wi < 16; wi += GRID_BLOCKS) {
        stats_item(pbuf + 5*262144, st + 1280, wi, smem);
        __syncthreads();
    }
    grid.sync();

    // ---- P10: down -- bn(buf0,st0,g0,b0)|bn(buf2,st2,g2,b2)|bn(buf5,st5,g3,b3)
    for (int wi = bid; wi < 256; wi += GRID_BLOCKS) {
        down_item(pbuf,            st,        gam,       bet,
                  pbuf + 2*262144, st + 512,  gam + 256, bet + 256,
                  pbuf + 5*262144, st + 1280, gam + 384, bet + 384,
                  dW, db, out, wi, smem);
        __syncthreads();
    }
}

// ---------------------------------------------------------------------------
extern "C" void kernel_launch(void* const* d_in, const int* in_sizes, int n_in,
                              void* d_out, int out_size, void* d_ws, size_t ws_size,
                              hipStream_t stream)
{
    (void)in_sizes; (void)n_in; (void)out_size; (void)ws_size;
    const float* verts = (const float*)d_in[0];
    const float* x     = (const float*)d_in[1];
    const float* convW = (const float*)d_in[2];
    const float* convB = (const float*)d_in[3];
    const float* dirs  = (const float*)d_in[4];
    const float* gam   = (const float*)d_in[5];
    const float* bet   = (const float*)d_in[6];
    const float* dW    = (const float*)d_in[7];
    const float* db    = (const float*)d_in[8];
    float* out = (float*)d_out;

    char* ws = (char*)d_ws;
    int*   idxb = (int*)(ws);                    //  819200 B : (2048,100)
    float* sdn  = (float*)(ws + 819200);         //    9216 B : (6,3,128)
    float* st   = (float*)(ws + 828416);         //    6144 B : 6 x 256
    float* fo   = (float*)(ws + 834560);         // 6291456 B : 3 x (2048,256)
    float* pbuf = (float*)(ws + 7126016);        // 6291456 B : 6 x (2048,128)

    void* args[] = {
        (void*)&verts, (void*)&x, (void*)&convW, (void*)&convB, (void*)&dirs,
        (void*)&gam, (void*)&bet, (void*)&dW, (void*)&db, (void*)&out,
        (void*)&idxb, (void*)&sdn, (void*)&st, (void*)&fo, (void*)&pbuf
    };
    hipLaunchCooperativeKernel((const void*)mega_kernel,
                               dim3(GRID_BLOCKS), dim3(256), args, 0, stream);
}

// Round 12
// 189.097 us; speedup vs baseline: 4.0854x; 4.0854x over previous
//
#include <hip/hip_runtime.h>

// ---------------------------------------------------------------------------
// GEMM body (chunked-LDS W): out[r0..r0+7, :256] = bn_relu?(in) @ W + bias.
// 8 rows/block, 256 threads = 2 rows x 4 cols. W staged through LDS in
// 16-k chunks (16 KB) so all 4 waves share one L2 read of W (per-CU W
// traffic 524 KB -> 131 KB; round-10 form was per-CU-L2-BW bound).
// smem layout: rows 4096 B | wch 16384 B | scale 512 B | shift 512 B = 21504.
// ---------------------------------------------------------------------------
__device__ __forceinline__ void do_gemm(
    const float* __restrict__ in, const float* __restrict__ st,
    const float* __restrict__ gm, const float* __restrict__ bt,
    const float* __restrict__ W, const float* __restrict__ bi,
    float* __restrict__ out, int rb, char* smemc)
{
    float* rows  = (float*)smemc;           // 1024 floats
    float* wch   = rows + 1024;             // 4096 floats (16 KB)
    float* scale = wch + 4096;              // 128
    float* shift = scale + 128;             // 128
    int t = threadIdx.x;
    if (t < 128) {
        float sc = 1.0f, sf = 0.0f;
        if (st) {
            float mu  = st[t] * (1.0f/2048.0f);
            float var = st[128+t] * (1.0f/2048.0f) - mu*mu;
            sc = rsqrtf(var + 1e-5f) * gm[t];
            sf = bt[t] - mu*sc;
        }
        scale[t] = sc; shift[t] = sf;
    }
    __syncthreads();
    int r0 = rb * 8;
    {                                       // stage 8 rows = 256 float4
        float4 v = ((const float4*)(in + r0*128))[t];
        if (st) {
            int c4 = (t & 31) << 2;
            v.x = fmaxf(v.x*scale[c4  ] + shift[c4  ], 0.0f);
            v.y = fmaxf(v.y*scale[c4+1] + shift[c4+1], 0.0f);
            v.z = fmaxf(v.z*scale[c4+2] + shift[c4+2], 0.0f);
            v.w = fmaxf(v.w*scale[c4+3] + shift[c4+3], 0.0f);
        }
        ((float4*)rows)[t] = v;
    }
    int cb = t & 63, rp = (t >> 6) << 1;    // rows rp, rp+1 (wave-uniform rp)
    const float* a0r = rows + rp*128;
    const float* a1r = a0r + 128;
    const float4* W4 = (const float4*)W;
    float4* wch4 = (float4*)wch;
    float4 acc0 = make_float4(0.f,0.f,0.f,0.f);
    float4 acc1 = make_float4(0.f,0.f,0.f,0.f);
    for (int c = 0; c < 8; ++c) {           // 8 chunks x 16 k
        __syncthreads();                    // (1st iter also covers rows staging)
        #pragma unroll
        for (int i = 0; i < 4; ++i)
            wch4[t + 256*i] = W4[c*1024 + t + 256*i];
        __syncthreads();
        int kb = c*16;
        #pragma unroll
        for (int k = 0; k < 16; k += 4) {
            float4 a0 = *(const float4*)(a0r + kb + k);
            float4 a1 = *(const float4*)(a1r + kb + k);
            float4 w;
            w = wch4[(k+0)*64+cb];
            acc0.x += a0.x*w.x; acc0.y += a0.x*w.y; acc0.z += a0.x*w.z; acc0.w += a0.x*w.w;
            acc1.x += a1.x*w.x; acc1.y += a1.x*w.y; acc1.z += a1.x*w.z; acc1.w += a1.x*w.w;
            w = wch4[(k+1)*64+cb];
            acc0.x += a0.y*w.x; acc0.y += a0.y*w.y; acc0.z += a0.y*w.z; acc0.w += a0.y*w.w;
            acc1.x += a1.y*w.x; acc1.y += a1.y*w.y; acc1.z += a1.y*w.z; acc1.w += a1.y*w.w;
            w = wch4[(k+2)*64+cb];
            acc0.x += a0.z*w.x; acc0.y += a0.z*w.y; acc0.z += a0.z*w.z; acc0.w += a0.z*w.w;
            acc1.x += a1.z*w.x; acc1.y += a1.z*w.y; acc1.z += a1.z*w.z; acc1.w += a1.z*w.w;
            w = wch4[(k+3)*64+cb];
            acc0.x += a0.w*w.x; acc0.y += a0.w*w.y; acc0.z += a0.w*w.z; acc0.w += a0.w*w.w;
            acc1.x += a1.w*w.x; acc1.y += a1.w*w.y; acc1.z += a1.w*w.z; acc1.w += a1.w*w.w;
        }
    }
    float4 b4 = ((const float4*)bi)[cb];
    acc0.x += b4.x; acc0.y += b4.y; acc0.z += b4.z; acc0.w += b4.w;
    acc1.x += b4.x; acc1.y += b4.y; acc1.z += b4.z; acc1.w += b4.w;
    ((float4*)out)[(r0+rp  )*64 + cb] = acc0;
    ((float4*)out)[(r0+rp+1)*64 + cb] = acc1;
}

// ---------------------------------------------------------------------------
// K1: wave-sync knn (blocks 0..511) + gemmA (512..1279: 3 slots x 256) +
// zero st (1280..1285) + dirs norm (1286). knn algorithm verified r8-r11.
// ---------------------------------------------------------------------------
__global__ void k1_kernel(const float* __restrict__ verts, const float* __restrict__ dirs,
                          const float* __restrict__ x,
                          const float* __restrict__ convW, const float* __restrict__ convB,
                          int* __restrict__ idxout, float* __restrict__ sdn,
                          float* __restrict__ st, float* __restrict__ fo)
{
    __shared__ __align__(16) char smem[21504];
    int t = threadIdx.x;
    int blk = blockIdx.x;

    if (blk >= 1280) {
        if (blk == 1286) {
            for (int i = t; i < 768; i += 256) {
                int l = i >> 7, k = i & 127;
                float a = dirs[l*384 + k];
                float b = dirs[l*384 + 128 + k];
                float c = dirs[l*384 + 256 + k];
                float nrm = sqrtf(a*a + b*b + c*c);
                float inv = 1.0f / fmaxf(nrm, 1e-12f);
                sdn[l*384 + k]       = a*inv;
                sdn[l*384 + 128 + k] = b*inv;
                sdn[l*384 + 256 + k] = c*inv;
            }
        } else {
            st[(blk - 1280)*256 + t] = 0.0f;
        }
        return;
    }
    if (blk >= 512) {
        int g = blk - 512;
        int s = g >> 8, rb = g & 255;
        int wi = (s==0) ? 0 : (s==1) ? 1 : 3;
        do_gemm(x, (const float*)0, (const float*)0, (const float*)0,
                convW + wi*32768, convB + wi*256, fo + s*524288, rb, smem);
        return;
    }

    // ---------------- knn: one wave per vertex ----------------
    float* xs  = (float*)smem;
    float* ys  = xs + 1024;
    float* zs  = ys + 1024;
    float* sqs = zs + 1024;
    unsigned int* histBase = (unsigned int*)(smem + 16384);
    unsigned int* selBase  = (unsigned int*)(smem + 20480);

    int w = t >> 6, l = t & 63;
    int vglob = blk*4 + w;
    int b = vglob >> 10;
    int v = vglob & 1023;
    unsigned long long* keys = (unsigned long long*)smem + w*256;  // alias xs/ys
    unsigned int* hist = histBase + w*256;
    unsigned int* sel  = selBase + w*4;

    const float* vb = verts + b * 3072;
    for (int i = t; i < 1024; i += 256) {
        float xx = vb[i*3+0], yy = vb[i*3+1], zz = vb[i*3+2];
        xs[i] = xx; ys[i] = yy; zs[i] = zz;
        sqs[i] = xx*xx + yy*yy + zz*zz;
    }
    __syncthreads();

    float cx = xs[v], cy = ys[v], cz = zs[v], csq = sqs[v];
    unsigned long long K16[16];
    #pragma unroll
    for (int q = 0; q < 16; ++q) {
        int j = q*64 + l;
        float dot = cx*xs[j] + cy*ys[j] + cz*zs[j];
        float d = -2.0f*dot + csq + sqs[j];
        unsigned int u = __float_as_uint(d);
        u = (u & 0x80000000u) ? ~u : (u | 0x80000000u);
        K16[q] = (((unsigned long long)u) << 32) | (unsigned long long)j;
    }
    #pragma unroll
    for (int i = 0; i < 4; ++i) hist[l*4 + i] = 0u;
    __syncthreads();

    #pragma unroll
    for (int q = 0; q < 16; ++q)
        atomicAdd(&hist[(unsigned int)(K16[q] >> 56)], 1u);
    __syncthreads();

    {
        unsigned int h0 = hist[l*4], h1 = hist[l*4+1], h2 = hist[l*4+2], h3 = hist[l*4+3];
        unsigned int c1 = h0, c2 = h0+h1, c3 = h0+h1+h2, T = c3+h3;
        unsigned int xacc = T;
        #pragma unroll
        for (int off = 1; off < 64; off <<= 1) {
            unsigned int y = __shfl_up(xacc, off, 64);
            if (l >= off) xacc += y;
        }
        unsigned int P = xacc - T;
        unsigned int ex[4] = {P, P+c1, P+c2, P+c3};
        unsigned int hh[4] = {h0, h1, h2, h3};
        #pragma unroll
        for (int i = 0; i < 4; ++i) {
            if (ex[i] < 101u && ex[i] + hh[i] >= 101u) {
                sel[0] = (unsigned int)(l*4 + i);
                sel[1] = 101u - ex[i];
            }
        }
    }
    __syncthreads();
    unsigned int P8 = sel[0], rank2 = sel[1];
    #pragma unroll
    for (int i = 0; i < 4; ++i) hist[l*4 + i] = 0u;
    __syncthreads();

    #pragma unroll
    for (int q = 0; q < 16; ++q)
        if ((unsigned int)(K16[q] >> 56) == P8)
            atomicAdd(&hist[(unsigned int)(K16[q] >> 48) & 0xFFu], 1u);
    __syncthreads();

    {
        unsigned int h0 = hist[l*4], h1 = hist[l*4+1], h2 = hist[l*4+2], h3 = hist[l*4+3];
        unsigned int c1 = h0, c2 = h0+h1, c3 = h0+h1+h2, T = c3+h3;
        unsigned int xacc = T;
        #pragma unroll
        for (int off = 1; off < 64; off <<= 1) {
            unsigned int y = __shfl_up(xacc, off, 64);
            if (l >= off) xacc += y;
        }
        unsigned int P = xacc - T;
        unsigned int ex[4] = {P, P+c1, P+c2, P+c3};
        unsigned int hh[4] = {h0, h1, h2, h3};
        #pragma unroll
        for (int i = 0; i < 4; ++i) {
            if (ex[i] < rank2 && ex[i] + hh[i] >= rank2) {
                sel[2] = (P8 << 8) | (unsigned int)(l*4 + i);
                sel[3] = 0u;
            }
        }
    }
    __syncthreads();
    unsigned int P16 = sel[2];

    #pragma unroll
    for (int q = 0; q < 16; ++q) {
        if ((unsigned int)(K16[q] >> 48) <= P16) {
            unsigned int pos = atomicAdd(&sel[3], 1u);
            if (pos < 256u) keys[pos] = K16[q];
        }
    }
    __syncthreads();
    unsigned int cnt = sel[3];

    unsigned long long K[4];
    #pragma unroll
    for (int q = 0; q < 4; ++q) {
        unsigned int e = (unsigned int)(l*4 + q);
        K[q] = (e < cnt) ? keys[e] : 0xFFFFFFFFFFFFFFFFULL;
    }

    auto cswap = [&](int qa, int qb, int k) {
        int e = (l << 2) + qa;
        bool up = ((e & k) == 0);
        unsigned long long a = K[qa], bb2 = K[qb];
        unsigned long long mn = a < bb2 ? a : bb2;
        unsigned long long mx = a < bb2 ? bb2 : a;
        K[qa] = up ? mn : mx;
        K[qb] = up ? mx : mn;
    };
    #pragma unroll
    for (int k = 2; k <= 256; k <<= 1) {
        for (int j = k >> 1; j >= 4; j >>= 1) {
            int lj = j >> 2;
            #pragma unroll
            for (int q = 0; q < 4; ++q) {
                unsigned long long other = __shfl_xor(K[q], lj, 64);
                int e = (l << 2) + q;
                bool up = ((e & k) == 0);
                bool lower = ((l & lj) == 0);
                bool takeMin = (lower == up);
                unsigned long long mn = K[q] < other ? K[q] : other;
                unsigned long long mx = K[q] < other ? other : K[q];
                K[q] = takeMin ? mn : mx;
            }
        }
        if (k >= 4) { cswap(0, 2, k); cswap(1, 3, k); }
        cswap(0, 1, k); cswap(2, 3, k);
    }

    #pragma unroll
    for (int q = 0; q < 4; ++q) {
        int e = l*4 + q;
        if (e >= 1 && e <= 100)
            idxout[vglob*100 + (e-1)] = (int)(K[q] & 0xFFFFFFFFu);
    }
}

// ---------------------------------------------------------------------------
// Agg: 256 threads = 2 rows/block (half-block per row; verified in r11 mega).
// prebn[r,k] = fo[r,k] + max_n relu(d_n.sd_k)*fo[nbr,128+k]. Unroll 5.
// grid (1024, nslots).
// ---------------------------------------------------------------------------
__global__ void agg_kernel(const int* __restrict__ idx, const float* __restrict__ verts,
                           const float* __restrict__ sdn, const float* __restrict__ fo,
                           int n0, int n1, int n2, int d0, int d1, int d2,
                           float* o0, float* o1, float* o2)
{
    __shared__ float4 ds4s[200];
    __shared__ int jss[200];
    int slot = blockIdx.y;
    int n  = slot==0 ? n0 : slot==1 ? n1 : n2;
    int dI = slot==0 ? d0 : slot==1 ? d1 : d2;
    float* outp = slot==0 ? o0 : slot==1 ? o1 : o2;
    const float* fos = fo + slot * 524288;
    const float* sd = sdn + dI * 384;

    int t = threadIdx.x;
    int h = t >> 7, tt = t & 127;
    float4* ds4 = ds4s + h*100;
    int* js = jss + h*100;
    int r = blockIdx.x*2 + h;
    int b = r >> 10;

    if (tt < n) {
        int j = idx[r*100 + tt];
        js[tt] = j;
        const float* pj = verts + (b*1024 + j)*3;
        const float* pv = verts + r*3;
        float dx = pj[0]-pv[0], dy = pj[1]-pv[1], dz = pj[2]-pv[2];
        float nm = sqrtf(dx*dx + dy*dy + dz*dz);
        float inv = 1.0f / fmaxf(nm, 1e-12f);
        ds4[tt] = make_float4(dx*inv, dy*inv, dz*inv, 0.0f);
    }
    __syncthreads();
    float s0 = sd[tt], s1 = sd[128+tt], s2 = sd[256+tt];
    int bb = b * 1024;
    float m = -3.0e38f;
    for (int q = 0; q < n; q += 5) {
        float th[5];
        const float* p[5];
        #pragma unroll
        for (int u = 0; u < 5; ++u) {
            float4 dq = ds4[q+u];
            th[u] = fmaxf(dq.x*s0 + dq.y*s1 + dq.z*s2, 0.0f);
            p[u] = fos + (size_t)(bb + js[q+u])*256 + 128 + tt;
        }
        float vv[5];
        #pragma unroll
        for (int u = 0; u < 5; ++u) vv[u] = *p[u];
        #pragma unroll
        for (int u = 0; u < 5; ++u) m = fmaxf(m, th[u]*vv[u]);
    }
    outp[r*128 + tt] = fos[r*256 + tt] + m;
}

// ---------------------------------------------------------------------------
// BN stats: per-channel sum/sumsq over 2048 rows. grid (16, nslots).
// ---------------------------------------------------------------------------
__global__ void stats_kernel(const float* p0, const float* p1, const float* p2,
                             int i0, int i1, int i2, float* stats)
{
    int slot = blockIdx.y;
    const float* p = slot==0 ? p0 : slot==1 ? p1 : p2;
    float* st = stats + (slot==0 ? i0 : slot==1 ? i1 : i2) * 256;
    __shared__ float s1[256], s2[256];
    int t = threadIdx.x, k = t & 127, half = t >> 7;
    int r0 = blockIdx.x * 128;
    float sum = 0.0f, sq = 0.0f;
    for (int s = 0; s < 64; ++s) {
        float x = p[(r0 + half + 2*s)*128 + k];
        sum += x; sq += x*x;
    }
    s1[t] = sum; s2[t] = sq;
    __syncthreads();
    if (t < 128) {
        atomicAdd(&st[k],     s1[t] + s1[t+128]);
        atomicAdd(&st[128+k], s2[t] + s2[t+128]);
    }
}

// ---------------------------------------------------------------------------
// Standalone gemm, up to 2 slots via blockIdx.y. grid (256, nslots), 256 thr.
// ---------------------------------------------------------------------------
__global__ void gemm2_kernel(
    const float* inA, const float* stA, const float* gA, const float* beA,
    const float* WA, const float* biA, float* foA,
    const float* inB, const float* stB, const float* gB, const float* beB,
    const float* WB, const float* biB, float* foB)
{
    __shared__ __align__(16) char smem[21504];
    if (blockIdx.y == 0)
        do_gemm(inA, stA, gA, beA, WA, biA, foA, blockIdx.x, smem);
    else
        do_gemm(inB, stB, gB, beB, WB, biB, foB, blockIdx.x, smem);
}

// ---------------------------------------------------------------------------
// Down-proj (chunked-LDS W): row = [bn(p0)|bn(p1)|bn(p2)] (384) @ dW + db.
// 8 rows/block (256 blocks), 24 chunks of 16 k. LDS ~31.3 KB.
// ---------------------------------------------------------------------------
__global__ void down_kernel(
    const float* __restrict__ p0, const float* __restrict__ st0,
    const float* __restrict__ g0, const float* __restrict__ be0,
    const float* __restrict__ p1, const float* __restrict__ st1,
    const float* __restrict__ g1, const float* __restrict__ be1,
    const float* __restrict__ p2, const float* __restrict__ st2,
    const float* __restrict__ g2, const float* __restrict__ be2,
    const float* __restrict__ dW, const float* __restrict__ db,
    float* __restrict__ out)
{
    __shared__ float rows[8*384];          // 12288 B
    __shared__ float wch[16*256];          // 16384 B
    __shared__ float scale[384], shift[384];
    int t = threadIdx.x;
    int r0 = blockIdx.x * 8;
    for (int c = t; c < 384; c += 256) {
        int seg = c >> 7, cc = c & 127;
        const float* stp = seg==0 ? st0 : seg==1 ? st1 : st2;
        const float* g   = seg==0 ? g0  : seg==1 ? g1  : g2;
        const float* be  = seg==0 ? be0 : seg==1 ? be1 : be2;
        float mu  = stp[cc] * (1.0f/2048.0f);
        float var = stp[128+cc] * (1.0f/2048.0f) - mu*mu;
        float s = rsqrtf(var + 1e-5f) * g[cc];
        scale[c] = s;
        shift[c] = be[cc] - mu*s;
    }
    __syncthreads();
    for (int q = t; q < 768; q += 256) {   // 8 rows x 96 float4
        int row = q / 96, rem = q - row*96;
        int c4 = rem << 2;
        int seg = c4 >> 7, cc = c4 & 127;
        const float* ps = seg==0 ? p0 : seg==1 ? p1 : p2;
        float4 v = *(const float4*)(ps + (r0+row)*128 + cc);
        v.x = fmaxf(v.x*scale[c4  ] + shift[c4  ], 0.0f);
        v.y = fmaxf(v.y*scale[c4+1] + shift[c4+1], 0.0f);
        v.z = fmaxf(v.z*scale[c4+2] + shift[c4+2], 0.0f);
        v.w = fmaxf(v.w*scale[c4+3] + shift[c4+3], 0.0f);
        *(float4*)&rows[row*384 + c4] = v;
    }
    int cb = t & 63, rp = (t >> 6) << 1;
    const float* a0r = rows + rp*384;
    const float* a1r = a0r + 384;
    const float4* W4 = (const float4*)dW;
    float4* wch4 = (float4*)wch;
    float4 acc0 = make_float4(0.f,0.f,0.f,0.f);
    float4 acc1 = make_float4(0.f,0.f,0.f,0.f);
    for (int c = 0; c < 24; ++c) {
        __syncthreads();                   // (1st iter also covers rows staging)
        #pragma unroll
        for (int i = 0; i < 4; ++i)
            wch4[t + 256*i] = W4[c*1024 + t + 256*i];
        __syncthreads();
        int kb = c*16;
        #pragma unroll
        for (int k = 0; k < 16; k += 4) {
            float4 a0 = *(const float4*)(a0r + kb + k);
            float4 a1 = *(const float4*)(a1r + kb + k);
            float4 w;
            w = wch4[(k+0)*64+cb];
            acc0.x += a0.x*w.x; acc0.y += a0.x*w.y; acc0.z += a0.x*w.z; acc0.w += a0.x*w.w;
            acc1.x += a1.x*w.x; acc1.y += a1.x*w.y; acc1.z += a1.x*w.z; acc1.w += a1.x*w.w;
            w = wch4[(k+1)*64+cb];
            acc0.x += a0.y*w.x; acc0.y += a0.y*w.y; acc0.z += a0.y*w.z; acc0.w += a0.y*w.w;
            acc1.x += a1.y*w.x; acc1.y += a1.y*w.y; acc1.z += a1.y*w.z; acc1.w += a1.y*w.w;
            w = wch4[(k+2)*64+cb];
            acc0.x += a0.z*w.x; acc0.y += a0.z*w.y; acc0.z += a0.z*w.z; acc0.w += a0.z*w.w;
            acc1.x += a1.z*w.x; acc1.y += a1.z*w.y; acc1.z += a1.z*w.z; acc1.w += a1.z*w.w;
            w = wch4[(k+3)*64+cb];
            acc0.x += a0.w*w.x; acc0.y += a0.w*w.y; acc0.z += a0.w*w.z; acc0.w += a0.w*w.w;
            acc1.x += a1.w*w.x; acc1.y += a1.w*w.y; acc1.z += a1.w*w.z; acc1.w += a1.w*w.w;
        }
    }
    float4 b4 = ((const float4*)db)[cb];
    float4 o0, o1;
    o0.x = fmaxf(acc0.x + b4.x, 0.0f); o0.y = fmaxf(acc0.y + b4.y, 0.0f);
    o0.z = fmaxf(acc0.z + b4.z, 0.0f); o0.w = fmaxf(acc0.w + b4.w, 0.0f);
    o1.x = fmaxf(acc1.x + b4.x, 0.0f); o1.y = fmaxf(acc1.y + b4.y, 0.0f);
    o1.z = fmaxf(acc1.z + b4.z, 0.0f); o1.w = fmaxf(acc1.w + b4.w, 0.0f);
    ((float4*)out)[(r0+rp  )*64 + cb] = o0;
    ((float4*)out)[(r0+rp+1)*64 + cb] = o1;
}

// ---------------------------------------------------------------------------
extern "C" void kernel_launch(void* const* d_in, const int* in_sizes, int n_in,
                              void* d_out, int out_size, void* d_ws, size_t ws_size,
                              hipStream_t stream)
{
    (void)in_sizes; (void)n_in; (void)out_size; (void)ws_size;
    const float* verts = (const float*)d_in[0];
    const float* x     = (const float*)d_in[1];
    const float* convW = (const float*)d_in[2];
    const float* convB = (const float*)d_in[3];
    const float* dirs  = (const float*)d_in[4];
    const float* gam   = (const float*)d_in[5];
    const float* bet   = (const float*)d_in[6];
    const float* dW    = (const float*)d_in[7];
    const float* db    = (const float*)d_in[8];
    float* out = (float*)d_out;

    char* ws = (char*)d_ws;
    int*   idxb = (int*)(ws);                    //  819200 B : (2048,100)
    float* sdn  = (float*)(ws + 819200);         //    9216 B : (6,3,128)
    float* st   = (float*)(ws + 828416);         //    6144 B : 6 x 256
    float* fo   = (float*)(ws + 834560);         // 6291456 B : 3 x (2048,256)
    float* p0   = (float*)(ws + 7126016);        // 1 MiB each: (2048,128)
    float* p1   = (float*)(ws + 8174592);
    float* p2   = (float*)(ws + 9223168);
    float* p3   = (float*)(ws + 10271744);
    float* p4   = (float*)(ws + 11320320);
    float* p5   = (float*)(ws + 12368896);       // total ~12.8 MiB

    const float* nf = (const float*)0;
    float* nw = (float*)0;
    float* st0 = st,        *st1 = st + 256,  *st2 = st + 512;
    float* st3 = st + 768,  *st4 = st + 1024, *st5 = st + 1280;

    // K1: knn + gemmA (L0,L1,L3 from x) + st zero + dirs norm
    k1_kernel<<<1287, 256, 0, stream>>>(verts, dirs, x, convW, convB,
                                        idxb, sdn, st, fo);
    // K2: aggA -> p0 (n5,d0), p1 (n20,d1), p3 (n100,d3)
    agg_kernel<<<dim3(1024,3), 256, 0, stream>>>(
        idxb, verts, sdn, fo, 5, 20, 100, 0, 1, 3, p0, p1, p3);
    // K3: statsA
    stats_kernel<<<dim3(16,3), 256, 0, stream>>>(p0, p1, p3, 0, 1, 3, st);
    // K4: gemmB: L2 from bn(p1,st1,g1,b1); L4 from bn(p3,st3,g3,b3)
    gemm2_kernel<<<dim3(256,2), 256, 0, stream>>>(
        p1, st1, gam + 128, bet + 128, convW + 65536,  convB + 512,  fo,
        p3, st3, gam + 384, bet + 384, convW + 131072, convB + 1024, fo + 524288);
    // K5: aggB -> p2 (n20,d2), p4 (n100,d4)
    agg_kernel<<<dim3(1024,2), 256, 0, stream>>>(
        idxb, verts, sdn, fo, 20, 100, 0, 2, 4, 0, p2, p4, nw);
    // K6: statsB
    stats_kernel<<<dim3(16,2), 256, 0, stream>>>(p2, p4, nf, 2, 4, 0, st);
    // K7: gemmC: L5-conv (params3) from bn(p4,st4,g4,b4)
    gemm2_kernel<<<dim3(256,1), 256, 0, stream>>>(
        p4, st4, gam + 512, bet + 512, convW + 98304, convB + 768, fo,
        nf, nf, nf, nf, nf, nf, nw);
    // K8: aggC -> p5 (n100,d3)
    agg_kernel<<<dim3(1024,1), 256, 0, stream>>>(
        idxb, verts, sdn, fo, 100, 0, 0, 3, 0, 0, p5, nw, nw);
    // K9: statsC
    stats_kernel<<<dim3(16,1), 256, 0, stream>>>(p5, nf, nf, 5, 0, 0, st);
    // K10: down: bn(p0,st0,g0,b0) | bn(p2,st2,g2,b2) | bn(p5,st5,g3,b3)
    down_kernel<<<256, 256, 0, stream>>>(
        p0, st0, gam, bet,
        p2, st2, gam + 256, bet + 256,
        p5, st5, gam + 384, bet + 384,
        dW, db, out);
}

// Round 13
// 187.761 us; speedup vs baseline: 4.1145x; 1.0071x over previous
//
#include <hip/hip_runtime.h>

// ---------------------------------------------------------------------------
// Workspace:
//   idxb 0        : (2048,100) int       819200
//   sdn  819200   : (6,3,128)              9216
//   stp  828416   : 6 layers x 32 banks x 256 f32  196608   (BN partials)
//   fo   1025024  : 3 x (2048,256)       6291456
//   p0.. 7316480  : 6 x (2048,128)       6291456
// BN stats: agg blocks atomically add (val, val^2) into bank (row&31);
// consumers (gemm/down) reduce the 32 banks. Eliminates 3 stats launches.
// ---------------------------------------------------------------------------

// ---------------------------------------------------------------------------
// GEMM body (chunked-LDS W): out[r0..r0+7, :256] = bn_relu?(in) @ W + bias.
// 8 rows/block, 256 threads = 2 rows x 4 cols. stp: 32-bank partials.
// ---------------------------------------------------------------------------
__device__ __forceinline__ void do_gemm(
    const float* __restrict__ in, const float* __restrict__ stp,
    const float* __restrict__ gm, const float* __restrict__ bt,
    const float* __restrict__ W, const float* __restrict__ bi,
    float* __restrict__ out, int rb, char* smemc)
{
    float* rows  = (float*)smemc;           // 1024 floats
    float* wch   = rows + 1024;             // 4096 floats (16 KB)
    float* scale = wch + 4096;              // 128
    float* shift = scale + 128;             // 128
    int t = threadIdx.x;
    if (t < 128) {
        float sc = 1.0f, sf = 0.0f;
        if (stp) {
            float sm = 0.0f, sq = 0.0f;
            #pragma unroll 8
            for (int bk = 0; bk < 32; ++bk) {
                sm += stp[bk*256 + t];
                sq += stp[bk*256 + 128 + t];
            }
            float mu  = sm * (1.0f/2048.0f);
            float var = sq * (1.0f/2048.0f) - mu*mu;
            sc = rsqrtf(var + 1e-5f) * gm[t];
            sf = bt[t] - mu*sc;
        }
        scale[t] = sc; shift[t] = sf;
    }
    __syncthreads();
    int r0 = rb * 8;
    {
        float4 v = ((const float4*)(in + r0*128))[t];
        if (stp) {
            int c4 = (t & 31) << 2;
            v.x = fmaxf(v.x*scale[c4  ] + shift[c4  ], 0.0f);
            v.y = fmaxf(v.y*scale[c4+1] + shift[c4+1], 0.0f);
            v.z = fmaxf(v.z*scale[c4+2] + shift[c4+2], 0.0f);
            v.w = fmaxf(v.w*scale[c4+3] + shift[c4+3], 0.0f);
        }
        ((float4*)rows)[t] = v;
    }
    int cb = t & 63, rp = (t >> 6) << 1;
    const float* a0r = rows + rp*128;
    const float* a1r = a0r + 128;
    const float4* W4 = (const float4*)W;
    float4* wch4 = (float4*)wch;
    float4 acc0 = make_float4(0.f,0.f,0.f,0.f);
    float4 acc1 = make_float4(0.f,0.f,0.f,0.f);
    for (int c = 0; c < 8; ++c) {
        __syncthreads();
        #pragma unroll
        for (int i = 0; i < 4; ++i)
            wch4[t + 256*i] = W4[c*1024 + t + 256*i];
        __syncthreads();
        int kb = c*16;
        #pragma unroll
        for (int k = 0; k < 16; k += 4) {
            float4 a0 = *(const float4*)(a0r + kb + k);
            float4 a1 = *(const float4*)(a1r + kb + k);
            float4 w;
            w = wch4[(k+0)*64+cb];
            acc0.x += a0.x*w.x; acc0.y += a0.x*w.y; acc0.z += a0.x*w.z; acc0.w += a0.x*w.w;
            acc1.x += a1.x*w.x; acc1.y += a1.x*w.y; acc1.z += a1.x*w.z; acc1.w += a1.x*w.w;
            w = wch4[(k+1)*64+cb];
            acc0.x += a0.y*w.x; acc0.y += a0.y*w.y; acc0.z += a0.y*w.z; acc0.w += a0.y*w.w;
            acc1.x += a1.y*w.x; acc1.y += a1.y*w.y; acc1.z += a1.y*w.z; acc1.w += a1.y*w.w;
            w = wch4[(k+2)*64+cb];
            acc0.x += a0.z*w.x; acc0.y += a0.z*w.y; acc0.z += a0.z*w.z; acc0.w += a0.z*w.w;
            acc1.x += a1.z*w.x; acc1.y += a1.z*w.y; acc1.z += a1.z*w.z; acc1.w += a1.z*w.w;
            w = wch4[(k+3)*64+cb];
            acc0.x += a0.w*w.x; acc0.y += a0.w*w.y; acc0.z += a0.w*w.z; acc0.w += a0.w*w.w;
            acc1.x += a1.w*w.x; acc1.y += a1.w*w.y; acc1.z += a1.w*w.z; acc1.w += a1.w*w.w;
        }
    }
    float4 b4 = ((const float4*)bi)[cb];
    acc0.x += b4.x; acc0.y += b4.y; acc0.z += b4.z; acc0.w += b4.w;
    acc1.x += b4.x; acc1.y += b4.y; acc1.z += b4.z; acc1.w += b4.w;
    ((float4*)out)[(r0+rp  )*64 + cb] = acc0;
    ((float4*)out)[(r0+rp+1)*64 + cb] = acc1;
}

// ---------------------------------------------------------------------------
// K1: wave-sync knn (0..511) + gemmA (512..1279) + zero stp (1280..1471) +
// dirs norm (1472). knn algorithm verified r8-r12.
// ---------------------------------------------------------------------------
__global__ void k1_kernel(const float* __restrict__ verts, const float* __restrict__ dirs,
                          const float* __restrict__ x,
                          const float* __restrict__ convW, const float* __restrict__ convB,
                          int* __restrict__ idxout, float* __restrict__ sdn,
                          float* __restrict__ stp, float* __restrict__ fo)
{
    __shared__ __align__(16) char smem[21504];
    int t = threadIdx.x;
    int blk = blockIdx.x;

    if (blk >= 1280) {
        if (blk == 1472) {
            for (int i = t; i < 768; i += 256) {
                int l = i >> 7, k = i & 127;
                float a = dirs[l*384 + k];
                float b = dirs[l*384 + 128 + k];
                float c = dirs[l*384 + 256 + k];
                float nrm = sqrtf(a*a + b*b + c*c);
                float inv = 1.0f / fmaxf(nrm, 1e-12f);
                sdn[l*384 + k]       = a*inv;
                sdn[l*384 + 128 + k] = b*inv;
                sdn[l*384 + 256 + k] = c*inv;
            }
        } else {
            stp[(blk - 1280)*256 + t] = 0.0f;     // 192 blocks x 256 = 49152
        }
        return;
    }
    if (blk >= 512) {
        int g = blk - 512;
        int s = g >> 8, rb = g & 255;
        int wi = (s==0) ? 0 : (s==1) ? 1 : 3;
        do_gemm(x, (const float*)0, (const float*)0, (const float*)0,
                convW + wi*32768, convB + wi*256, fo + s*524288, rb, smem);
        return;
    }

    // ---------------- knn: one wave per vertex ----------------
    float* xs  = (float*)smem;
    float* ys  = xs + 1024;
    float* zs  = ys + 1024;
    float* sqs = zs + 1024;
    unsigned int* histBase = (unsigned int*)(smem + 16384);
    unsigned int* selBase  = (unsigned int*)(smem + 20480);

    int w = t >> 6, l = t & 63;
    int vglob = blk*4 + w;
    int b = vglob >> 10;
    int v = vglob & 1023;
    unsigned long long* keys = (unsigned long long*)smem + w*256;  // alias xs/ys
    unsigned int* hist = histBase + w*256;
    unsigned int* sel  = selBase + w*4;

    const float* vb = verts + b * 3072;
    for (int i = t; i < 1024; i += 256) {
        float xx = vb[i*3+0], yy = vb[i*3+1], zz = vb[i*3+2];
        xs[i] = xx; ys[i] = yy; zs[i] = zz;
        sqs[i] = xx*xx + yy*yy + zz*zz;
    }
    __syncthreads();

    float cx = xs[v], cy = ys[v], cz = zs[v], csq = sqs[v];
    unsigned long long K16[16];
    #pragma unroll
    for (int q = 0; q < 16; ++q) {
        int j = q*64 + l;
        float dot = cx*xs[j] + cy*ys[j] + cz*zs[j];
        float d = -2.0f*dot + csq + sqs[j];
        unsigned int u = __float_as_uint(d);
        u = (u & 0x80000000u) ? ~u : (u | 0x80000000u);
        K16[q] = (((unsigned long long)u) << 32) | (unsigned long long)j;
    }
    #pragma unroll
    for (int i = 0; i < 4; ++i) hist[l*4 + i] = 0u;
    __syncthreads();

    #pragma unroll
    for (int q = 0; q < 16; ++q)
        atomicAdd(&hist[(unsigned int)(K16[q] >> 56)], 1u);
    __syncthreads();

    {
        unsigned int h0 = hist[l*4], h1 = hist[l*4+1], h2 = hist[l*4+2], h3 = hist[l*4+3];
        unsigned int c1 = h0, c2 = h0+h1, c3 = h0+h1+h2, T = c3+h3;
        unsigned int xacc = T;
        #pragma unroll
        for (int off = 1; off < 64; off <<= 1) {
            unsigned int y = __shfl_up(xacc, off, 64);
            if (l >= off) xacc += y;
        }
        unsigned int P = xacc - T;
        unsigned int ex[4] = {P, P+c1, P+c2, P+c3};
        unsigned int hh[4] = {h0, h1, h2, h3};
        #pragma unroll
        for (int i = 0; i < 4; ++i) {
            if (ex[i] < 101u && ex[i] + hh[i] >= 101u) {
                sel[0] = (unsigned int)(l*4 + i);
                sel[1] = 101u - ex[i];
            }
        }
    }
    __syncthreads();
    unsigned int P8 = sel[0], rank2 = sel[1];
    #pragma unroll
    for (int i = 0; i < 4; ++i) hist[l*4 + i] = 0u;
    __syncthreads();

    #pragma unroll
    for (int q = 0; q < 16; ++q)
        if ((unsigned int)(K16[q] >> 56) == P8)
            atomicAdd(&hist[(unsigned int)(K16[q] >> 48) & 0xFFu], 1u);
    __syncthreads();

    {
        unsigned int h0 = hist[l*4], h1 = hist[l*4+1], h2 = hist[l*4+2], h3 = hist[l*4+3];
        unsigned int c1 = h0, c2 = h0+h1, c3 = h0+h1+h2, T = c3+h3;
        unsigned int xacc = T;
        #pragma unroll
        for (int off = 1; off < 64; off <<= 1) {
            unsigned int y = __shfl_up(xacc, off, 64);
            if (l >= off) xacc += y;
        }
        unsigned int P = xacc - T;
        unsigned int ex[4] = {P, P+c1, P+c2, P+c3};
        unsigned int hh[4] = {h0, h1, h2, h3};
        #pragma unroll
        for (int i = 0; i < 4; ++i) {
            if (ex[i] < rank2 && ex[i] + hh[i] >= rank2) {
                sel[2] = (P8 << 8) | (unsigned int)(l*4 + i);
                sel[3] = 0u;
            }
        }
    }
    __syncthreads();
    unsigned int P16 = sel[2];

    #pragma unroll
    for (int q = 0; q < 16; ++q) {
        if ((unsigned int)(K16[q] >> 48) <= P16) {
            unsigned int pos = atomicAdd(&sel[3], 1u);
            if (pos < 256u) keys[pos] = K16[q];
        }
    }
    __syncthreads();
    unsigned int cnt = sel[3];

    unsigned long long K[4];
    #pragma unroll
    for (int q = 0; q < 4; ++q) {
        unsigned int e = (unsigned int)(l*4 + q);
        K[q] = (e < cnt) ? keys[e] : 0xFFFFFFFFFFFFFFFFULL;
    }

    auto cswap = [&](int qa, int qb, int k) {
        int e = (l << 2) + qa;
        bool up = ((e & k) == 0);
        unsigned long long a = K[qa], bb2 = K[qb];
        unsigned long long mn = a < bb2 ? a : bb2;
        unsigned long long mx = a < bb2 ? bb2 : a;
        K[qa] = up ? mn : mx;
        K[qb] = up ? mx : mn;
    };
    #pragma unroll
    for (int k = 2; k <= 256; k <<= 1) {
        for (int j = k >> 1; j >= 4; j >>= 1) {
            int lj = j >> 2;
            #pragma unroll
            for (int q = 0; q < 4; ++q) {
                unsigned long long other = __shfl_xor(K[q], lj, 64);
                int e = (l << 2) + q;
                bool up = ((e & k) == 0);
                bool lower = ((l & lj) == 0);
                bool takeMin = (lower == up);
                unsigned long long mn = K[q] < other ? K[q] : other;
                unsigned long long mx = K[q] < other ? other : K[q];
                K[q] = takeMin ? mn : mx;
            }
        }
        if (k >= 4) { cswap(0, 2, k); cswap(1, 3, k); }
        cswap(0, 1, k); cswap(2, 3, k);
    }

    #pragma unroll
    for (int q = 0; q < 4; ++q) {
        int e = l*4 + q;
        if (e >= 1 && e <= 100)
            idxout[vglob*100 + (e-1)] = (int)(K[q] & 0xFFFFFFFFu);
    }
}

// ---------------------------------------------------------------------------
// Agg + fused BN-partials: 256 threads = 2 rows/block. After writing the
// row, each thread adds (val, val^2) into stp bank (row & 31) (64 adds per
// address across the launch; fire-and-forget atomics).
// ---------------------------------------------------------------------------
__global__ void agg_kernel(const int* __restrict__ idx, const float* __restrict__ verts,
                           const float* __restrict__ sdn, const float* __restrict__ fo,
                           int n0, int n1, int n2, int d0, int d1, int d2,
                           float* o0, float* o1, float* o2,
                           float* s0p, float* s1p, float* s2p)
{
    __shared__ float4 ds4s[200];
    __shared__ int jss[200];
    int slot = blockIdx.y;
    int n  = slot==0 ? n0 : slot==1 ? n1 : n2;
    int dI = slot==0 ? d0 : slot==1 ? d1 : d2;
    float* outp = slot==0 ? o0 : slot==1 ? o1 : o2;
    float* stp  = slot==0 ? s0p : slot==1 ? s1p : s2p;
    const float* fos = fo + slot * 524288;
    const float* sd = sdn + dI * 384;

    int t = threadIdx.x;
    int h = t >> 7, tt = t & 127;
    float4* ds4 = ds4s + h*100;
    int* js = jss + h*100;
    int r = blockIdx.x*2 + h;
    int b = r >> 10;

    if (tt < n) {
        int j = idx[r*100 + tt];
        js[tt] = j;
        const float* pj = verts + (b*1024 + j)*3;
        const float* pv = verts + r*3;
        float dx = pj[0]-pv[0], dy = pj[1]-pv[1], dz = pj[2]-pv[2];
        float nm = sqrtf(dx*dx + dy*dy + dz*dz);
        float inv = 1.0f / fmaxf(nm, 1e-12f);
        ds4[tt] = make_float4(dx*inv, dy*inv, dz*inv, 0.0f);
    }
    __syncthreads();
    float s0 = sd[tt], s1 = sd[128+tt], s2 = sd[256+tt];
    int bb = b * 1024;
    float m = -3.0e38f;
    for (int q = 0; q < n; q += 5) {
        float th[5];
        const float* p[5];
        #pragma unroll
        for (int u = 0; u < 5; ++u) {
            float4 dq = ds4[q+u];
            th[u] = fmaxf(dq.x*s0 + dq.y*s1 + dq.z*s2, 0.0f);
            p[u] = fos + (size_t)(bb + js[q+u])*256 + 128 + tt;
        }
        float vv[5];
        #pragma unroll
        for (int u = 0; u < 5; ++u) vv[u] = *p[u];
        #pragma unroll
        for (int u = 0; u < 5; ++u) m = fmaxf(m, th[u]*vv[u]);
    }
    float val = fos[r*256 + tt] + m;
    outp[r*128 + tt] = val;
    float* bank = stp + (r & 31)*256;
    atomicAdd(&bank[tt], val);
    atomicAdd(&bank[128+tt], val*val);
}

// ---------------------------------------------------------------------------
// Standalone gemm, up to 2 slots via blockIdx.y. grid (256, nslots), 256 thr.
// ---------------------------------------------------------------------------
__global__ void gemm2_kernel(
    const float* inA, const float* stA, const float* gA, const float* beA,
    const float* WA, const float* biA, float* foA,
    const float* inB, const float* stB, const float* gB, const float* beB,
    const float* WB, const float* biB, float* foB)
{
    __shared__ __align__(16) char smem[21504];
    if (blockIdx.y == 0)
        do_gemm(inA, stA, gA, beA, WA, biA, foA, blockIdx.x, smem);
    else
        do_gemm(inB, stB, gB, beB, WB, biB, foB, blockIdx.x, smem);
}

// ---------------------------------------------------------------------------
// Down-proj (chunked-LDS W): [bn(p0)|bn(p1)|bn(p2)] (384) @ dW + db, relu.
// 8 rows/block (256 blocks). BN scales from 32-bank partials.
// ---------------------------------------------------------------------------
__global__ void down_kernel(
    const float* __restrict__ p0, const float* __restrict__ s0p,
    const float* __restrict__ g0, const float* __restrict__ be0,
    const float* __restrict__ p1, const float* __restrict__ s1p,
    const float* __restrict__ g1, const float* __restrict__ be1,
    const float* __restrict__ p2, const float* __restrict__ s2p,
    const float* __restrict__ g2, const float* __restrict__ be2,
    const float* __restrict__ dW, const float* __restrict__ db,
    float* __restrict__ out)
{
    __shared__ float rows[8*384];
    __shared__ float wch[16*256];
    __shared__ float scale[384], shift[384];
    int t = threadIdx.x;
    int r0 = blockIdx.x * 8;
    for (int c = t; c < 384; c += 256) {
        int seg = c >> 7, cc = c & 127;
        const float* stp = seg==0 ? s0p : seg==1 ? s1p : s2p;
        const float* g   = seg==0 ? g0  : seg==1 ? g1  : g2;
        const float* be  = seg==0 ? be0 : seg==1 ? be1 : be2;
        float sm = 0.0f, sq = 0.0f;
        #pragma unroll 8
        for (int bk = 0; bk < 32; ++bk) {
            sm += stp[bk*256 + cc];
            sq += stp[bk*256 + 128 + cc];
        }
        float mu  = sm * (1.0f/2048.0f);
        float var = sq * (1.0f/2048.0f) - mu*mu;
        float s = rsqrtf(var + 1e-5f) * g[cc];
        scale[c] = s;
        shift[c] = be[cc] - mu*s;
    }
    __syncthreads();
    for (int q = t; q < 768; q += 256) {
        int row = q / 96, rem = q - row*96;
        int c4 = rem << 2;
        int seg = c4 >> 7, cc = c4 & 127;
        const float* ps = seg==0 ? p0 : seg==1 ? p1 : p2;
        float4 v = *(const float4*)(ps + (r0+row)*128 + cc);
        v.x = fmaxf(v.x*scale[c4  ] + shift[c4  ], 0.0f);
        v.y = fmaxf(v.y*scale[c4+1] + shift[c4+1], 0.0f);
        v.z = fmaxf(v.z*scale[c4+2] + shift[c4+2], 0.0f);
        v.w = fmaxf(v.w*scale[c4+3] + shift[c4+3], 0.0f);
        *(float4*)&rows[row*384 + c4] = v;
    }
    int cb = t & 63, rp = (t >> 6) << 1;
    const float* a0r = rows + rp*384;
    const float* a1r = a0r + 384;
    const float4* W4 = (const float4*)dW;
    float4* wch4 = (float4*)wch;
    float4 acc0 = make_float4(0.f,0.f,0.f,0.f);
    float4 acc1 = make_float4(0.f,0.f,0.f,0.f);
    for (int c = 0; c < 24; ++c) {
        __syncthreads();
        #pragma unroll
        for (int i = 0; i < 4; ++i)
            wch4[t + 256*i] = W4[c*1024 + t + 256*i];
        __syncthreads();
        int kb = c*16;
        #pragma unroll
        for (int k = 0; k < 16; k += 4) {
            float4 a0 = *(const float4*)(a0r + kb + k);
            float4 a1 = *(const float4*)(a1r + kb + k);
            float4 w;
            w = wch4[(k+0)*64+cb];
            acc0.x += a0.x*w.x; acc0.y += a0.x*w.y; acc0.z += a0.x*w.z; acc0.w += a0.x*w.w;
            acc1.x += a1.x*w.x; acc1.y += a1.x*w.y; acc1.z += a1.x*w.z; acc1.w += a1.x*w.w;
            w = wch4[(k+1)*64+cb];
            acc0.x += a0.y*w.x; acc0.y += a0.y*w.y; acc0.z += a0.y*w.z; acc0.w += a0.y*w.w;
            acc1.x += a1.y*w.x; acc1.y += a1.y*w.y; acc1.z += a1.y*w.z; acc1.w += a1.y*w.w;
            w = wch4[(k+2)*64+cb];
            acc0.x += a0.z*w.x; acc0.y += a0.z*w.y; acc0.z += a0.z*w.z; acc0.w += a0.z*w.w;
            acc1.x += a1.z*w.x; acc1.y += a1.z*w.y; acc1.z += a1.z*w.z; acc1.w += a1.z*w.w;
            w = wch4[(k+3)*64+cb];
            acc0.x += a0.w*w.x; acc0.y += a0.w*w.y; acc0.z += a0.w*w.z; acc0.w += a0.w*w.w;
            acc1.x += a1.w*w.x; acc1.y += a1.w*w.y; acc1.z += a1.w*w.z; acc1.w += a1.w*w.w;
        }
    }
    float4 b4 = ((const float4*)db)[cb];
    float4 o0, o1;
    o0.x = fmaxf(acc0.x + b4.x, 0.0f); o0.y = fmaxf(acc0.y + b4.y, 0.0f);
    o0.z = fmaxf(acc0.z + b4.z, 0.0f); o0.w = fmaxf(acc0.w + b4.w, 0.0f);
    o1.x = fmaxf(acc1.x + b4.x, 0.0f); o1.y = fmaxf(acc1.y + b4.y, 0.0f);
    o1.z = fmaxf(acc1.z + b4.z, 0.0f); o1.w = fmaxf(acc1.w + b4.w, 0.0f);
    ((float4*)out)[(r0+rp  )*64 + cb] = o0;
    ((float4*)out)[(r0+rp+1)*64 + cb] = o1;
}

// ---------------------------------------------------------------------------
extern "C" void kernel_launch(void* const* d_in, const int* in_sizes, int n_in,
                              void* d_out, int out_size, void* d_ws, size_t ws_size,
                              hipStream_t stream)
{
    (void)in_sizes; (void)n_in; (void)out_size; (void)ws_size;
    const float* verts = (const float*)d_in[0];
    const float* x     = (const float*)d_in[1];
    const float* convW = (const float*)d_in[2];
    const float* convB = (const float*)d_in[3];
    const float* dirs  = (const float*)d_in[4];
    const float* gam   = (const float*)d_in[5];
    const float* bet   = (const float*)d_in[6];
    const float* dW    = (const float*)d_in[7];
    const float* db    = (const float*)d_in[8];
    float* out = (float*)d_out;

    char* ws = (char*)d_ws;
    int*   idxb = (int*)(ws);
    float* sdn  = (float*)(ws + 819200);
    float* stp  = (float*)(ws + 828416);         // 6 x 32 x 256 f32
    float* fo   = (float*)(ws + 1025024);        // 3 x (2048,256)
    float* p0   = (float*)(ws + 7316480);
    float* p1   = (float*)(ws + 8365056);
    float* p2   = (float*)(ws + 9413632);
    float* p3   = (float*)(ws + 10462208);
    float* p4   = (float*)(ws + 11510784);
    float* p5   = (float*)(ws + 12559360);       // end ~13.0 MiB

    const float* nf = (const float*)0;
    float* nw = (float*)0;
    float* stL0 = stp,         *stL1 = stp + 8192, *stL2 = stp + 16384;
    float* stL3 = stp + 24576, *stL4 = stp + 32768, *stL5 = stp + 40960;

    // K1: knn + gemmA (L0,L1,L3 from x) + zero stp + dirs norm
    k1_kernel<<<1473, 256, 0, stream>>>(verts, dirs, x, convW, convB,
                                        idxb, sdn, stp, fo);
    // K2: aggA -> p0 (n5,d0,stL0), p1 (n20,d1,stL1), p3 (n100,d3,stL3)
    agg_kernel<<<dim3(1024,3), 256, 0, stream>>>(
        idxb, verts, sdn, fo, 5, 20, 100, 0, 1, 3,
        p0, p1, p3, stL0, stL1, stL3);
    // K3: gemmB: L2 from bn(p1,stL1,g1,b1); L4 from bn(p3,stL3,g3,b3)
    gemm2_kernel<<<dim3(256,2), 256, 0, stream>>>(
        p1, stL1, gam + 128, bet + 128, convW + 65536,  convB + 512,  fo,
        p3, stL3, gam + 384, bet + 384, convW + 131072, convB + 1024, fo + 524288);
    // K4: aggB -> p2 (n20,d2,stL2), p4 (n100,d4,stL4)
    agg_kernel<<<dim3(1024,2), 256, 0, stream>>>(
        idxb, verts, sdn, fo, 20, 100, 0, 2, 4, 0,
        p2, p4, nw, stL2, stL4, nw);
    // K5: gemmC: L5-conv (params3) from bn(p4,stL4,g4,b4)
    gemm2_kernel<<<dim3(256,1), 256, 0, stream>>>(
        p4, stL4, gam + 512, bet + 512, convW + 98304, convB + 768, fo,
        nf, nf, nf, nf, nf, nf, nw);
    // K6: aggC -> p5 (n100,d3,stL5)
    agg_kernel<<<dim3(1024,1), 256, 0, stream>>>(
        idxb, verts, sdn, fo, 100, 0, 0, 3, 0, 0,
        p5, nw, nw, stL5, nw, nw);
    // K7: down: bn(p0,stL0,g0,b0) | bn(p2,stL2,g2,b2) | bn(p5,stL5,g3,b3)
    down_kernel<<<256, 256, 0, stream>>>(
        p0, stL0, gam, bet,
        p2, stL2, gam + 256, bet + 256,
        p5, stL5, gam + 384, bet + 384,
        dW, db, out);
}